// Round 13
// baseline (366.503 us; speedup 1.0000x reference)
//
#include <hip/hip_runtime.h>

#define N_NODES 50000
#define N_EDGES 800000
#define F_INDIM 512
#define HID     256
#define N_CLS   64
#define K_STEPS 10
#define ALPHA_V 0.1f

#define NPB 28     // nodes per prop block (4 waves x 7)
#define NPW 7
#define ECAP 1536  // LDS edge-record capacity (mean 448, 12 KB)

typedef __attribute__((ext_vector_type(8))) short short8;
typedef __attribute__((ext_vector_type(4))) float f32x4;
typedef __attribute__((ext_vector_type(4))) unsigned short ushort4v;

__device__ __forceinline__ unsigned short f2bf(float f) {
  unsigned u = __builtin_bit_cast(unsigned, f);
  unsigned r = (u + 0x7fffu + ((u >> 16) & 1u)) >> 16;
  return (unsigned short)r;
}
__device__ __forceinline__ float bflo(unsigned g) {
  return __builtin_bit_cast(float, g << 16);
}
__device__ __forceinline__ float bfhi(unsigned g) {
  return __builtin_bit_cast(float, g & 0xffff0000u);
}

#define GLOAD_LDS16(g, l)                                                        \
  __builtin_amdgcn_global_load_lds(                                              \
      (const __attribute__((address_space(1))) unsigned int*)(g),                \
      (__attribute__((address_space(3))) unsigned int*)(l), 16, 0, 0)

// ---------------- edge dtype detection ----------------
__global__ void detect_kernel(const int* __restrict__ eb, int* __restrict__ flag) {
  __shared__ int any;
  if (threadIdx.x == 0) any = 0;
  __syncthreads();
  for (int j = threadIdx.x; j < 1024; j += 256) {
    if (eb[2 * j + 1] != 0) atomicOr(&any, 1);
  }
  __syncthreads();
  if (threadIdx.x == 0) flag[0] = any ? 0 : 1;  // 1 => int64 stride, 0 => int32
}

// ---------------- degree histogram over targets ----------------
__global__ void count_kernel(const int* __restrict__ eb, const int* __restrict__ flagp,
                             int* __restrict__ cnt) {
  int e = blockIdx.x * 256 + threadIdx.x;
  if (e >= N_EDGES) return;
  int sh = flagp[0];
  int c = eb[((size_t)(N_EDGES + e)) << sh];
  atomicAdd(&cnt[c], 1);
}

// ---------------- 3-kernel exclusive scan ----------------
__global__ void scan1_kernel(const int* __restrict__ cnt, int* __restrict__ ptr,
                             int* __restrict__ bsum) {
  __shared__ int sm[256];
  int t = threadIdx.x;
  int i = blockIdx.x * 256 + t;
  int v = (i < N_NODES) ? cnt[i] : 0;
  sm[t] = v;
  __syncthreads();
  for (int off = 1; off < 256; off <<= 1) {
    int x = sm[t];
    if (t >= off) x += sm[t - off];
    __syncthreads();
    sm[t] = x;
    __syncthreads();
  }
  int incl = sm[t];
  if (i < N_NODES) ptr[i] = incl - v;
  if (t == 255) bsum[blockIdx.x] = incl;
}

__global__ void scan2_kernel(int* __restrict__ bsum, int nblk) {
  __shared__ int sm[256];
  int t = threadIdx.x;
  int v = (t < nblk) ? bsum[t] : 0;
  sm[t] = v;
  __syncthreads();
  for (int off = 1; off < 256; off <<= 1) {
    int x = sm[t];
    if (t >= off) x += sm[t - off];
    __syncthreads();
    sm[t] = x;
    __syncthreads();
  }
  int incl = sm[t];
  if (t < nblk) bsum[t] = incl - v;
}

__global__ void scan3_kernel(int* __restrict__ ptr, const int* __restrict__ bsum) {
  int i = blockIdx.x * 256 + threadIdx.x;
  if (i < N_NODES) ptr[i] += bsum[i >> 8];
  if (i == 0) ptr[N_NODES] = N_EDGES;
}

// ---------------- dinv + selfw + cursor init ----------------
__global__ void dinv_kernel(const int* __restrict__ cnt, const int* __restrict__ ptr,
                            float* __restrict__ dinv, float* __restrict__ selfw,
                            int* __restrict__ cursor) {
  int i = blockIdx.x * 256 + threadIdx.x;
  if (i >= N_NODES) return;
  float di = rsqrtf((float)cnt[i] + 1.0f);
  dinv[i] = di;
  selfw[i] = (1.0f - ALPHA_V) * di * di;
  cursor[i] = ptr[i];
}

// ---------------- CSR fill (by target), packed (src, weight) ----------------
__global__ void fill_kernel(const int* __restrict__ eb, const int* __restrict__ flagp,
                            const float* __restrict__ dinv, int* __restrict__ cursor,
                            int2* __restrict__ epack) {
  int e = blockIdx.x * 256 + threadIdx.x;
  if (e >= N_EDGES) return;
  int sh = flagp[0];
  int r = eb[((size_t)e) << sh];
  int c = eb[((size_t)(N_EDGES + e)) << sh];
  int pos = atomicAdd(&cursor[c], 1);
  float w = (1.0f - ALPHA_V) * dinv[r] * dinv[c];
  epack[pos] = make_int2(r, __float_as_int(w));
}

// ---------------- weight transpose + bf16 prepass ----------------
__global__ void prep_w(const float* __restrict__ W1, const float* __restrict__ W2,
                       unsigned short* __restrict__ W1T, unsigned short* __restrict__ W2T) {
  int i = blockIdx.x * 256 + threadIdx.x;
  if (i < F_INDIM * HID) {
    int k = i >> 8, c = i & 255;
    W1T[(size_t)c * F_INDIM + k] = f2bf(W1[i]);
  }
  int j = i - F_INDIM * HID;
  if (j >= 0 && j < HID * N_CLS) {
    int k = j >> 6, c = j & 63;
    W2T[(size_t)c * HID + k] = f2bf(W2[j]);
  }
}

// ---------------- GEMM1: BM=64 BN=128 BK=64, 8 phases, LDS dbuf --------------
// Halved barrier-drain count vs BK=32; 16 MFMA/wave/phase. Swizzle: 8 granules
// of 16 B per 128-B row, g' = g ^ (row & 7) (<=2-way on all b128 accesses).
__global__ __launch_bounds__(256, 3) void gemm1_mfma(
    const float* __restrict__ A, const unsigned short* __restrict__ BT,
    const float* __restrict__ bias, unsigned short* __restrict__ H, int M) {
  __shared__ unsigned short Ab[2][64 * 64];    // 8 KB each
  __shared__ unsigned short Bb[2][128 * 64];   // 16 KB each
  const int t = threadIdx.x;
  const int wave = t >> 6, lane = t & 63;
  const int l15 = lane & 15, l4 = lane >> 4;
  const int row0 = blockIdx.x * 64, col0 = blockIdx.y * 128;

  f32x4 acc[8];
#pragma unroll
  for (int n = 0; n < 8; ++n) acc[n] = (f32x4)0.0f;

  const int NT = F_INDIM / 64;  // 8 phases

  // B: 128 rows x 64 k bf16 = 16 KB/buffer; 4 glds per wave (8 rows each).
  auto stageB = [&](int buf, int kt) {
#pragma unroll
    for (int i = 0; i < 4; ++i) {
      int row = wave * 32 + i * 8 + (lane >> 3);
      int g = lane & 7;
      int kg = g ^ (row & 7);
      const unsigned short* src = BT + (size_t)(col0 + row) * F_INDIM + kt * 64 + kg * 8;
      unsigned short* dst = &Bb[buf][(wave * 32 + i * 8) * 64];  // wave-uniform
      GLOAD_LDS16(src, dst);
    }
  };
  // A: 64 rows x 64 k fp32 = 16 KB; 4 contiguous f32x4 per thread.
  f32x4 ar[4];
  int arow[4], acol[4];
  auto loadA = [&](int kt) {
#pragma unroll
    for (int i = 0; i < 4; ++i) {
      int idx = (i * 256 + t) * 4;     // flat float idx in 64x64 tile
      int row = idx >> 6;
      int col = idx & 63;
      arow[i] = row; acol[i] = col;
      int gr = row0 + row;
      if (gr > M - 1) gr = M - 1;
      ar[i] = *(const f32x4*)(A + (size_t)gr * F_INDIM + kt * 64 + col);
    }
  };
  auto writeA = [&](int buf) {
#pragma unroll
    for (int i = 0; i < 4; ++i) {
      int row = arow[i], col = acol[i];
      int g = col >> 3;
      int gp = g ^ (row & 7);
      ushort4v o;
#pragma unroll
      for (int j = 0; j < 4; ++j) o[j] = f2bf(ar[i][j]);
      *(ushort4v*)(&Ab[buf][row * 64 + gp * 8 + (col & 7)]) = o;
    }
  };
  auto compute = [&](int buf) {
    int rowA = wave * 16 + l15;
#pragma unroll
    for (int ks = 0; ks < 2; ++ks) {
      int kc = ks * 4 + l4;
      short8 af = *(const short8*)(&Ab[buf][rowA * 64 + (kc ^ (rowA & 7)) * 8]);
#pragma unroll
      for (int n = 0; n < 8; ++n) {
        int c = n * 16 + l15;
        short8 bf = *(const short8*)(&Bb[buf][c * 64 + (kc ^ (c & 7)) * 8]);
        acc[n] = __builtin_amdgcn_mfma_f32_16x16x32_bf16(af, bf, acc[n], 0, 0, 0);
      }
    }
  };

  stageB(0, 0);
  loadA(0);
  writeA(0);
  __syncthreads();
#pragma unroll
  for (int kt = 0; kt < NT; ++kt) {
    int cur = kt & 1;
    if (kt + 1 < NT) {
      stageB(cur ^ 1, kt + 1);
      loadA(kt + 1);
    }
    compute(cur);
    if (kt + 1 < NT) writeA(cur ^ 1);
    __syncthreads();
  }

  float bv[8];
#pragma unroll
  for (int n = 0; n < 8; ++n) bv[n] = bias[col0 + n * 16 + l15];
#pragma unroll
  for (int i = 0; i < 4; ++i) {
    int grow = row0 + wave * 16 + l4 * 4 + i;
    if (grow >= M) continue;
#pragma unroll
    for (int n = 0; n < 8; ++n) {
      int gcol = col0 + n * 16 + l15;
      float v = fmaxf(acc[n][i] + bv[n], 0.0f);
      H[(size_t)grow * HID + gcol] = f2bf(v);
    }
  }
}

// ---------------- GEMM2: x0 = h @ W2 + b2 -> bf16 flat [N][64] ----------------
__global__ __launch_bounds__(256) void gemm2_mfma(
    const unsigned short* __restrict__ Hm, const unsigned short* __restrict__ BT,
    const float* __restrict__ bias, unsigned short* __restrict__ Ch,
    int roff, int M) {
  const int t = threadIdx.x;
  const int wave = t >> 6, lane = t & 63;
  const int l15 = lane & 15, l4 = lane >> 4;
  const int row0 = blockIdx.x * 64 + wave * 16;

  f32x4 acc[4];
#pragma unroll
  for (int n = 0; n < 4; ++n) acc[n] = (f32x4)0.0f;

  int gr = row0 + l15;
  if (gr > M - 1) gr = M - 1;
  const unsigned short* arow = Hm + (size_t)gr * HID + l4 * 8;

#pragma unroll
  for (int kt = 0; kt < HID / 32; ++kt) {
    short8 af = *(const short8*)(arow + kt * 32);
    short8 bf[4];
#pragma unroll
    for (int n = 0; n < 4; ++n)
      bf[n] = *(const short8*)(BT + (size_t)(n * 16 + l15) * HID + kt * 32 + l4 * 8);
#pragma unroll
    for (int n = 0; n < 4; ++n)
      acc[n] = __builtin_amdgcn_mfma_f32_16x16x32_bf16(af, bf[n], acc[n], 0, 0, 0);
  }

#pragma unroll
  for (int n = 0; n < 4; ++n) {
    int gcol = n * 16 + l15;
    float bv = bias[gcol];
#pragma unroll
    for (int i = 0; i < 4; ++i) {
      int grow = row0 + l4 * 4 + i;
      if (grow < M) {
        float v = acc[n][i] + bv;
        Ch[(size_t)(roff + grow) * N_CLS + gcol] = f2bf(v);
      }
    }
  }
}

// ---------------- propagation: quad-edge gathers (4 edges / instruction) -----
template <bool LAST>
__global__ __launch_bounds__(256) void prop_step(
    const unsigned int* __restrict__ zin, const unsigned int* __restrict__ x0h,
    const float* __restrict__ selfw, const int* __restrict__ ptr,
    const int2* __restrict__ epack, unsigned int* __restrict__ zout,
    float* __restrict__ outf) {
  __shared__ int2 erec[ECAP];
  __shared__ int lptr[NPB + 1];
  __shared__ float lsw[NPB];

  const int tid = threadIdx.x;
  const int n0 = blockIdx.x * NPB;
  int nEnd = N_NODES - n0;
  if (nEnd > NPB) nEnd = NPB;

  if (tid <= nEnd) lptr[tid] = ptr[n0 + tid];
  if (tid < nEnd) lsw[tid] = selfw[n0 + tid];
  __syncthreads();
  const int base = lptr[0];
  const int cnt = lptr[nEnd] - base;
  for (int i = tid; i < cnt && i < ECAP; i += 256) erec[i] = epack[base + i];
  __syncthreads();

  const int wv = tid >> 6, lane = tid & 63;
  const int eg = lane >> 4, c4 = lane & 15;

  auto run = [&](auto getrec) {
    for (int ni = wv * NPW; ni < wv * NPW + NPW; ++ni) {
      if (ni >= nEnd) break;
      const int node = n0 + ni;
      float a0 = 0.f, a1 = 0.f, a2 = 0.f, a3 = 0.f;
      if (eg == 0) {
        uint2 zs = *(const uint2*)&zin[(size_t)node * 32 + 2 * c4];
        uint2 xs = *(const uint2*)&x0h[(size_t)node * 32 + 2 * c4];
        float sw = lsw[ni];
        a0 = fmaf(sw, bflo(zs.x), ALPHA_V * bflo(xs.x));
        a1 = fmaf(sw, bfhi(zs.x), ALPHA_V * bfhi(xs.x));
        a2 = fmaf(sw, bflo(zs.y), ALPHA_V * bflo(xs.y));
        a3 = fmaf(sw, bfhi(zs.y), ALPHA_V * bfhi(xs.y));
      }
      int e = lptr[ni] - base, e1 = lptr[ni + 1] - base;
      for (; e + 16 <= e1; e += 16) {  // 16 edges = 4 gather instructions
        int2 p[4];
#pragma unroll
        for (int j = 0; j < 4; ++j) p[j] = getrec(e + 4 * j + eg);
        uint2 g[4];
#pragma unroll
        for (int j = 0; j < 4; ++j)
          g[j] = *(const uint2*)&zin[(size_t)p[j].x * 32 + 2 * c4];
#pragma unroll
        for (int j = 0; j < 4; ++j) {
          float w = __int_as_float(p[j].y);
          a0 = fmaf(w, bflo(g[j].x), a0);
          a1 = fmaf(w, bfhi(g[j].x), a1);
          a2 = fmaf(w, bflo(g[j].y), a2);
          a3 = fmaf(w, bfhi(g[j].y), a3);
        }
      }
      if (e < e1) {  // masked tail (dup loads merge in cache)
        int2 p[4];
        float m[4];
#pragma unroll
        for (int j = 0; j < 4; ++j) {
          int gi = e + 4 * j + eg;
          bool ok = gi < e1;
          p[j] = getrec(ok ? gi : e);
          m[j] = ok ? 1.0f : 0.0f;
        }
        uint2 g[4];
#pragma unroll
        for (int j = 0; j < 4; ++j)
          g[j] = *(const uint2*)&zin[(size_t)p[j].x * 32 + 2 * c4];
#pragma unroll
        for (int j = 0; j < 4; ++j) {
          float w = m[j] * __int_as_float(p[j].y);
          a0 = fmaf(w, bflo(g[j].x), a0);
          a1 = fmaf(w, bfhi(g[j].x), a1);
          a2 = fmaf(w, bflo(g[j].y), a2);
          a3 = fmaf(w, bfhi(g[j].y), a3);
        }
      }
      a0 += __shfl_xor(a0, 16); a0 += __shfl_xor(a0, 32);
      a1 += __shfl_xor(a1, 16); a1 += __shfl_xor(a1, 32);
      a2 += __shfl_xor(a2, 16); a2 += __shfl_xor(a2, 32);
      a3 += __shfl_xor(a3, 16); a3 += __shfl_xor(a3, 32);
      if (eg == 0) {
        if (LAST) {
          *(float4*)(outf + (size_t)node * 64 + 4 * c4) =
              make_float4(a0, a1, a2, a3);
        } else {
          uint2 o;
          o.x = (unsigned)f2bf(a0) | ((unsigned)f2bf(a1) << 16);
          o.y = (unsigned)f2bf(a2) | ((unsigned)f2bf(a3) << 16);
          *(uint2*)&zout[(size_t)node * 32 + 2 * c4] = o;
        }
      }
    }
  };

  if (cnt <= ECAP) {
    run([&](int i) { return erec[i]; });
  } else {
    run([&](int i) { return epack[base + i]; });  // fallback (≈never)
  }
}

// ---------------- host launcher ----------------
extern "C" void kernel_launch(void* const* d_in, const int* in_sizes, int n_in,
                              void* d_out, int out_size, void* d_ws, size_t ws_size,
                              hipStream_t stream) {
  const float* x  = (const float*)d_in[0];
  const float* W1 = (const float*)d_in[1];
  const float* b1 = (const float*)d_in[2];
  const float* W2 = (const float*)d_in[3];
  const float* b2 = (const float*)d_in[4];
  const int*   eb = (const int*)d_in[5];
  float* out = (float*)d_out;

  char* ws = (char*)d_ws;
  size_t off = 0;
  auto alloc = [&](size_t bytes) -> void* {
    void* p = ws + off;
    off = (off + bytes + 255) & ~(size_t)255;
    return p;
  };

  int*   flagp  = (int*)alloc(256);
  int*   cnt    = (int*)alloc(N_NODES * sizeof(int));
  int*   ptr    = (int*)alloc((N_NODES + 1) * sizeof(int));
  int*   cursor = (int*)alloc(N_NODES * sizeof(int));
  int*   bsum   = (int*)alloc(256 * sizeof(int));
  float* dinv   = (float*)alloc(N_NODES * sizeof(float));
  float* selfw  = (float*)alloc(N_NODES * sizeof(float));
  int2*  epack  = (int2*)alloc((size_t)N_EDGES * sizeof(int2));
  unsigned short* W1T = (unsigned short*)alloc((size_t)HID * F_INDIM * sizeof(unsigned short));
  unsigned short* W2T = (unsigned short*)alloc((size_t)N_CLS * HID * sizeof(unsigned short));
  unsigned int* x0h = (unsigned int*)alloc((size_t)N_NODES * 32 * sizeof(unsigned int));
  unsigned int* z1  = (unsigned int*)alloc((size_t)N_NODES * 32 * sizeof(unsigned int));
  unsigned int* z2  = (unsigned int*)alloc((size_t)N_NODES * 32 * sizeof(unsigned int));

  int nchunks = 1;
  while (nchunks < 16) {
    size_t hbytes = (size_t)(N_NODES / nchunks) * HID * sizeof(unsigned short);
    if (off + hbytes <= ws_size) break;
    nchunks <<= 1;
  }
  int Mc = N_NODES / nchunks;
  unsigned short* h = (unsigned short*)alloc((size_t)Mc * HID * sizeof(unsigned short));

  hipMemsetAsync(cnt, 0, N_NODES * sizeof(int), stream);
  detect_kernel<<<1, 256, 0, stream>>>(eb, flagp);
  count_kernel<<<(N_EDGES + 255) / 256, 256, 0, stream>>>(eb, flagp, cnt);
  int nblk = (N_NODES + 255) / 256;
  scan1_kernel<<<nblk, 256, 0, stream>>>(cnt, ptr, bsum);
  scan2_kernel<<<1, 256, 0, stream>>>(bsum, nblk);
  scan3_kernel<<<nblk, 256, 0, stream>>>(ptr, bsum);
  dinv_kernel<<<nblk, 256, 0, stream>>>(cnt, ptr, dinv, selfw, cursor);
  fill_kernel<<<(N_EDGES + 255) / 256, 256, 0, stream>>>(eb, flagp, dinv, cursor, epack);
  prep_w<<<(F_INDIM * HID + HID * N_CLS + 255) / 256, 256, 0, stream>>>(W1, W2, W1T, W2T);

  for (int ci = 0; ci < nchunks; ++ci) {
    const float* Achunk = x + (size_t)ci * Mc * F_INDIM;
    dim3 g1((Mc + 63) / 64, HID / 128);
    gemm1_mfma<<<g1, 256, 0, stream>>>(Achunk, W1T, b1, h, Mc);
    dim3 g2((Mc + 63) / 64);
    gemm2_mfma<<<g2, 256, 0, stream>>>(h, W2T, b2,
        (unsigned short*)x0h, ci * Mc, Mc);
  }

  int pgrid = (N_NODES + NPB - 1) / NPB;  // 1786
  const unsigned int* zin = x0h;
  unsigned int* zo[2] = {z1, z2};
  for (int s = 0; s < K_STEPS - 1; ++s) {
    unsigned int* zout = zo[s & 1];
    prop_step<false><<<pgrid, 256, 0, stream>>>(zin, x0h, selfw, ptr, epack, zout, nullptr);
    zin = zout;
  }
  prop_step<true><<<pgrid, 256, 0, stream>>>(zin, x0h, selfw, ptr, epack, nullptr, out);
}

// Round 14
// 353.582 us; speedup vs baseline: 1.0365x; 1.0365x over previous
//
#include <hip/hip_runtime.h>

#define N_NODES 50000
#define N_EDGES 800000
#define F_INDIM 512
#define HID     256
#define N_CLS   64
#define K_STEPS 10
#define ALPHA_V 0.1f

#define NPB 28     // nodes per prop block (4 waves x 7)
#define NPW 7
#define ECAP 1536  // LDS edge-record capacity (mean 448, 12 KB)

typedef __attribute__((ext_vector_type(8))) short short8;
typedef __attribute__((ext_vector_type(4))) float f32x4;
typedef __attribute__((ext_vector_type(4))) unsigned short ushort4v;

__device__ __forceinline__ unsigned short f2bf(float f) {
  unsigned u = __builtin_bit_cast(unsigned, f);
  unsigned r = (u + 0x7fffu + ((u >> 16) & 1u)) >> 16;
  return (unsigned short)r;
}
__device__ __forceinline__ float bflo(unsigned g) {
  return __builtin_bit_cast(float, g << 16);
}
__device__ __forceinline__ float bfhi(unsigned g) {
  return __builtin_bit_cast(float, g & 0xffff0000u);
}

#define GLOAD_LDS16(g, l)                                                        \
  __builtin_amdgcn_global_load_lds(                                              \
      (const __attribute__((address_space(1))) unsigned int*)(g),                \
      (__attribute__((address_space(3))) unsigned int*)(l), 16, 0, 0)

// ---------------- edge dtype detection ----------------
__global__ void detect_kernel(const int* __restrict__ eb, int* __restrict__ flag) {
  __shared__ int any;
  if (threadIdx.x == 0) any = 0;
  __syncthreads();
  for (int j = threadIdx.x; j < 1024; j += 256) {
    if (eb[2 * j + 1] != 0) atomicOr(&any, 1);
  }
  __syncthreads();
  if (threadIdx.x == 0) flag[0] = any ? 0 : 1;  // 1 => int64 stride, 0 => int32
}

// ---------------- degree histogram over targets ----------------
__global__ void count_kernel(const int* __restrict__ eb, const int* __restrict__ flagp,
                             int* __restrict__ cnt) {
  int e = blockIdx.x * 256 + threadIdx.x;
  if (e >= N_EDGES) return;
  int sh = flagp[0];
  int c = eb[((size_t)(N_EDGES + e)) << sh];
  atomicAdd(&cnt[c], 1);
}

// ---------------- 3-kernel exclusive scan ----------------
__global__ void scan1_kernel(const int* __restrict__ cnt, int* __restrict__ ptr,
                             int* __restrict__ bsum) {
  __shared__ int sm[256];
  int t = threadIdx.x;
  int i = blockIdx.x * 256 + t;
  int v = (i < N_NODES) ? cnt[i] : 0;
  sm[t] = v;
  __syncthreads();
  for (int off = 1; off < 256; off <<= 1) {
    int x = sm[t];
    if (t >= off) x += sm[t - off];
    __syncthreads();
    sm[t] = x;
    __syncthreads();
  }
  int incl = sm[t];
  if (i < N_NODES) ptr[i] = incl - v;
  if (t == 255) bsum[blockIdx.x] = incl;
}

__global__ void scan2_kernel(int* __restrict__ bsum, int nblk) {
  __shared__ int sm[256];
  int t = threadIdx.x;
  int v = (t < nblk) ? bsum[t] : 0;
  sm[t] = v;
  __syncthreads();
  for (int off = 1; off < 256; off <<= 1) {
    int x = sm[t];
    if (t >= off) x += sm[t - off];
    __syncthreads();
    sm[t] = x;
    __syncthreads();
  }
  int incl = sm[t];
  if (t < nblk) bsum[t] = incl - v;
}

__global__ void scan3_kernel(int* __restrict__ ptr, const int* __restrict__ bsum) {
  int i = blockIdx.x * 256 + threadIdx.x;
  if (i < N_NODES) ptr[i] += bsum[i >> 8];
  if (i == 0) ptr[N_NODES] = N_EDGES;
}

// ---------------- dinv + selfw + cursor init ----------------
__global__ void dinv_kernel(const int* __restrict__ cnt, const int* __restrict__ ptr,
                            float* __restrict__ dinv, float* __restrict__ selfw,
                            int* __restrict__ cursor) {
  int i = blockIdx.x * 256 + threadIdx.x;
  if (i >= N_NODES) return;
  float di = rsqrtf((float)cnt[i] + 1.0f);
  dinv[i] = di;
  selfw[i] = (1.0f - ALPHA_V) * di * di;
  cursor[i] = ptr[i];
}

// ---------------- CSR fill (by target), packed (src, weight) ----------------
__global__ void fill_kernel(const int* __restrict__ eb, const int* __restrict__ flagp,
                            const float* __restrict__ dinv, int* __restrict__ cursor,
                            int2* __restrict__ epack) {
  int e = blockIdx.x * 256 + threadIdx.x;
  if (e >= N_EDGES) return;
  int sh = flagp[0];
  int r = eb[((size_t)e) << sh];
  int c = eb[((size_t)(N_EDGES + e)) << sh];
  int pos = atomicAdd(&cursor[c], 1);
  float w = (1.0f - ALPHA_V) * dinv[r] * dinv[c];
  epack[pos] = make_int2(r, __float_as_int(w));
}

// ---------------- weight transpose + bf16 prepass ----------------
__global__ void prep_w(const float* __restrict__ W1, const float* __restrict__ W2,
                       unsigned short* __restrict__ W1T, unsigned short* __restrict__ W2T) {
  int i = blockIdx.x * 256 + threadIdx.x;
  if (i < F_INDIM * HID) {
    int k = i >> 8, c = i & 255;
    W1T[(size_t)c * F_INDIM + k] = f2bf(W1[i]);
  }
  int j = i - F_INDIM * HID;
  if (j >= 0 && j < HID * N_CLS) {
    int k = j >> 6, c = j & 63;
    W2T[(size_t)c * HID + k] = f2bf(W2[j]);
  }
}

// ---------------- GEMM1: BM=64 BN=128 BK=32, all-glds staging, counted vmcnt -
// Per phase/wave: exactly 4 glds (2 A fp32 + 2 B bf16). Phase k+1's loads stay
// in flight across the raw barriers (vmcnt(4), never 0 until the last phase).
// A staged as fp32, converted to bf16 in compute. Swizzles: A g^(row&7) over
// 8 granules/row; B g^((row>>1)&3) over 4 granules/row (both <=2-way, free).
__global__ __launch_bounds__(256, 4) void gemm1_mfma(
    const float* __restrict__ A, const unsigned short* __restrict__ BT,
    const float* __restrict__ bias, unsigned short* __restrict__ H, int M) {
  __shared__ float Af[2][64 * 32];             // 8 KB each
  __shared__ unsigned short Bb[2][128 * 32];   // 8 KB each
  const int t = threadIdx.x;
  const int wave = t >> 6, lane = t & 63;
  const int l15 = lane & 15, l4 = lane >> 4;
  const int row0 = blockIdx.x * 64, col0 = blockIdx.y * 128;

  f32x4 acc[8];
#pragma unroll
  for (int n = 0; n < 8; ++n) acc[n] = (f32x4)0.0f;

  const int NT = F_INDIM / 32;  // 16 phases

  auto stageB = [&](int buf, int kt) {
#pragma unroll
    for (int i = 0; i < 2; ++i) {
      int row = wave * 32 + i * 16 + (lane >> 2);
      int g = lane & 3;
      int kg = g ^ ((row >> 1) & 3);
      const unsigned short* src = BT + (size_t)(col0 + row) * F_INDIM + kt * 32 + kg * 8;
      unsigned short* dst = &Bb[buf][(wave * 32 + i * 16) * 32];
      GLOAD_LDS16(src, dst);
    }
  };
  auto stageA = [&](int buf, int kt) {
#pragma unroll
    for (int i = 0; i < 2; ++i) {
      int row = wave * 16 + i * 8 + (lane >> 3);   // local row; 8 rows/instr
      int gr = row0 + row;
      if (gr > M - 1) gr = M - 1;
      int g = lane & 7;
      int gp = g ^ (row & 7);                      // pre-swizzled source granule
      const float* src = A + (size_t)gr * F_INDIM + kt * 32 + gp * 4;
      float* dst = &Af[buf][(wave * 16 + i * 8) * 32];  // wave-uniform, linear
      GLOAD_LDS16(src, dst);
    }
  };
  auto compute = [&](int buf) {
    int rowA = wave * 16 + l15;
    f32x4 a0 = *(const f32x4*)(&Af[buf][rowA * 32 + ((2 * l4 + 0) ^ (rowA & 7)) * 4]);
    f32x4 a1 = *(const f32x4*)(&Af[buf][rowA * 32 + ((2 * l4 + 1) ^ (rowA & 7)) * 4]);
    short8 af;
#pragma unroll
    for (int j = 0; j < 4; ++j) {
      af[j] = (short)f2bf(a0[j]);
      af[4 + j] = (short)f2bf(a1[j]);
    }
    short8 bf[8];
#pragma unroll
    for (int n = 0; n < 8; ++n) {
      int c = n * 16 + l15;
      bf[n] = *(const short8*)(&Bb[buf][c * 32 + (l4 ^ ((c >> 1) & 3)) * 8]);
    }
#pragma unroll
    for (int n = 0; n < 8; ++n)
      acc[n] = __builtin_amdgcn_mfma_f32_16x16x32_bf16(af, bf[n], acc[n], 0, 0, 0);
  };

  stageA(0, 0);
  stageB(0, 0);
#pragma unroll
  for (int kt = 0; kt < NT; ++kt) {
    int cur = kt & 1;
    if (kt + 1 < NT) {
      stageA(cur ^ 1, kt + 1);   // 2 glds
      stageB(cur ^ 1, kt + 1);   // 2 glds
      asm volatile("s_waitcnt vmcnt(4)" ::: "memory");  // phase kt's 4 landed
    } else {
      asm volatile("s_waitcnt vmcnt(0)" ::: "memory");  // final phase: drain
    }
    __builtin_amdgcn_s_barrier();   // all waves' phase-kt staging visible
    compute(cur);
    __builtin_amdgcn_s_barrier();   // guard buf reuse by phase kt+2 staging
  }

  float bv[8];
#pragma unroll
  for (int n = 0; n < 8; ++n) bv[n] = bias[col0 + n * 16 + l15];
#pragma unroll
  for (int i = 0; i < 4; ++i) {
    int grow = row0 + wave * 16 + l4 * 4 + i;
    if (grow >= M) continue;
#pragma unroll
    for (int n = 0; n < 8; ++n) {
      int gcol = col0 + n * 16 + l15;
      float v = fmaxf(acc[n][i] + bv[n], 0.0f);
      H[(size_t)grow * HID + gcol] = f2bf(v);
    }
  }
}

// ---------------- GEMM2: x0 = h @ W2 + b2 -> bf16 flat [N][64] ----------------
__global__ __launch_bounds__(256) void gemm2_mfma(
    const unsigned short* __restrict__ Hm, const unsigned short* __restrict__ BT,
    const float* __restrict__ bias, unsigned short* __restrict__ Ch,
    int roff, int M) {
  const int t = threadIdx.x;
  const int wave = t >> 6, lane = t & 63;
  const int l15 = lane & 15, l4 = lane >> 4;
  const int row0 = blockIdx.x * 64 + wave * 16;

  f32x4 acc[4];
#pragma unroll
  for (int n = 0; n < 4; ++n) acc[n] = (f32x4)0.0f;

  int gr = row0 + l15;
  if (gr > M - 1) gr = M - 1;
  const unsigned short* arow = Hm + (size_t)gr * HID + l4 * 8;

#pragma unroll
  for (int kt = 0; kt < HID / 32; ++kt) {
    short8 af = *(const short8*)(arow + kt * 32);
    short8 bf[4];
#pragma unroll
    for (int n = 0; n < 4; ++n)
      bf[n] = *(const short8*)(BT + (size_t)(n * 16 + l15) * HID + kt * 32 + l4 * 8);
#pragma unroll
    for (int n = 0; n < 4; ++n)
      acc[n] = __builtin_amdgcn_mfma_f32_16x16x32_bf16(af, bf[n], acc[n], 0, 0, 0);
  }

#pragma unroll
  for (int n = 0; n < 4; ++n) {
    int gcol = n * 16 + l15;
    float bv = bias[gcol];
#pragma unroll
    for (int i = 0; i < 4; ++i) {
      int grow = row0 + l4 * 4 + i;
      if (grow < M) {
        float v = acc[n][i] + bv;
        Ch[(size_t)(roff + grow) * N_CLS + gcol] = f2bf(v);
      }
    }
  }
}

// ---------------- propagation: quad-edge gathers (4 edges / instruction) -----
template <bool LAST>
__global__ __launch_bounds__(256) void prop_step(
    const unsigned int* __restrict__ zin, const unsigned int* __restrict__ x0h,
    const float* __restrict__ selfw, const int* __restrict__ ptr,
    const int2* __restrict__ epack, unsigned int* __restrict__ zout,
    float* __restrict__ outf) {
  __shared__ int2 erec[ECAP];
  __shared__ int lptr[NPB + 1];
  __shared__ float lsw[NPB];

  const int tid = threadIdx.x;
  const int n0 = blockIdx.x * NPB;
  int nEnd = N_NODES - n0;
  if (nEnd > NPB) nEnd = NPB;

  if (tid <= nEnd) lptr[tid] = ptr[n0 + tid];
  if (tid < nEnd) lsw[tid] = selfw[n0 + tid];
  __syncthreads();
  const int base = lptr[0];
  const int cnt = lptr[nEnd] - base;
  for (int i = tid; i < cnt && i < ECAP; i += 256) erec[i] = epack[base + i];
  __syncthreads();

  const int wv = tid >> 6, lane = tid & 63;
  const int eg = lane >> 4, c4 = lane & 15;

  auto run = [&](auto getrec) {
    for (int ni = wv * NPW; ni < wv * NPW + NPW; ++ni) {
      if (ni >= nEnd) break;
      const int node = n0 + ni;
      float a0 = 0.f, a1 = 0.f, a2 = 0.f, a3 = 0.f;
      if (eg == 0) {
        uint2 zs = *(const uint2*)&zin[(size_t)node * 32 + 2 * c4];
        uint2 xs = *(const uint2*)&x0h[(size_t)node * 32 + 2 * c4];
        float sw = lsw[ni];
        a0 = fmaf(sw, bflo(zs.x), ALPHA_V * bflo(xs.x));
        a1 = fmaf(sw, bfhi(zs.x), ALPHA_V * bfhi(xs.x));
        a2 = fmaf(sw, bflo(zs.y), ALPHA_V * bflo(xs.y));
        a3 = fmaf(sw, bfhi(zs.y), ALPHA_V * bfhi(xs.y));
      }
      int e = lptr[ni] - base, e1 = lptr[ni + 1] - base;
      for (; e + 16 <= e1; e += 16) {  // 16 edges = 4 gather instructions
        int2 p[4];
#pragma unroll
        for (int j = 0; j < 4; ++j) p[j] = getrec(e + 4 * j + eg);
        uint2 g[4];
#pragma unroll
        for (int j = 0; j < 4; ++j)
          g[j] = *(const uint2*)&zin[(size_t)p[j].x * 32 + 2 * c4];
#pragma unroll
        for (int j = 0; j < 4; ++j) {
          float w = __int_as_float(p[j].y);
          a0 = fmaf(w, bflo(g[j].x), a0);
          a1 = fmaf(w, bfhi(g[j].x), a1);
          a2 = fmaf(w, bflo(g[j].y), a2);
          a3 = fmaf(w, bfhi(g[j].y), a3);
        }
      }
      if (e < e1) {  // masked tail (dup loads merge in cache)
        int2 p[4];
        float m[4];
#pragma unroll
        for (int j = 0; j < 4; ++j) {
          int gi = e + 4 * j + eg;
          bool ok = gi < e1;
          p[j] = getrec(ok ? gi : e);
          m[j] = ok ? 1.0f : 0.0f;
        }
        uint2 g[4];
#pragma unroll
        for (int j = 0; j < 4; ++j)
          g[j] = *(const uint2*)&zin[(size_t)p[j].x * 32 + 2 * c4];
#pragma unroll
        for (int j = 0; j < 4; ++j) {
          float w = m[j] * __int_as_float(p[j].y);
          a0 = fmaf(w, bflo(g[j].x), a0);
          a1 = fmaf(w, bfhi(g[j].x), a1);
          a2 = fmaf(w, bflo(g[j].y), a2);
          a3 = fmaf(w, bfhi(g[j].y), a3);
        }
      }
      a0 += __shfl_xor(a0, 16); a0 += __shfl_xor(a0, 32);
      a1 += __shfl_xor(a1, 16); a1 += __shfl_xor(a1, 32);
      a2 += __shfl_xor(a2, 16); a2 += __shfl_xor(a2, 32);
      a3 += __shfl_xor(a3, 16); a3 += __shfl_xor(a3, 32);
      if (eg == 0) {
        if (LAST) {
          *(float4*)(outf + (size_t)node * 64 + 4 * c4) =
              make_float4(a0, a1, a2, a3);
        } else {
          uint2 o;
          o.x = (unsigned)f2bf(a0) | ((unsigned)f2bf(a1) << 16);
          o.y = (unsigned)f2bf(a2) | ((unsigned)f2bf(a3) << 16);
          *(uint2*)&zout[(size_t)node * 32 + 2 * c4] = o;
        }
      }
    }
  };

  if (cnt <= ECAP) {
    run([&](int i) { return erec[i]; });
  } else {
    run([&](int i) { return epack[base + i]; });  // fallback (≈never)
  }
}

// ---------------- host launcher ----------------
extern "C" void kernel_launch(void* const* d_in, const int* in_sizes, int n_in,
                              void* d_out, int out_size, void* d_ws, size_t ws_size,
                              hipStream_t stream) {
  const float* x  = (const float*)d_in[0];
  const float* W1 = (const float*)d_in[1];
  const float* b1 = (const float*)d_in[2];
  const float* W2 = (const float*)d_in[3];
  const float* b2 = (const float*)d_in[4];
  const int*   eb = (const int*)d_in[5];
  float* out = (float*)d_out;

  char* ws = (char*)d_ws;
  size_t off = 0;
  auto alloc = [&](size_t bytes) -> void* {
    void* p = ws + off;
    off = (off + bytes + 255) & ~(size_t)255;
    return p;
  };

  int*   flagp  = (int*)alloc(256);
  int*   cnt    = (int*)alloc(N_NODES * sizeof(int));
  int*   ptr    = (int*)alloc((N_NODES + 1) * sizeof(int));
  int*   cursor = (int*)alloc(N_NODES * sizeof(int));
  int*   bsum   = (int*)alloc(256 * sizeof(int));
  float* dinv   = (float*)alloc(N_NODES * sizeof(float));
  float* selfw  = (float*)alloc(N_NODES * sizeof(float));
  int2*  epack  = (int2*)alloc((size_t)N_EDGES * sizeof(int2));
  unsigned short* W1T = (unsigned short*)alloc((size_t)HID * F_INDIM * sizeof(unsigned short));
  unsigned short* W2T = (unsigned short*)alloc((size_t)N_CLS * HID * sizeof(unsigned short));
  unsigned int* x0h = (unsigned int*)alloc((size_t)N_NODES * 32 * sizeof(unsigned int));
  unsigned int* z1  = (unsigned int*)alloc((size_t)N_NODES * 32 * sizeof(unsigned int));
  unsigned int* z2  = (unsigned int*)alloc((size_t)N_NODES * 32 * sizeof(unsigned int));

  int nchunks = 1;
  while (nchunks < 16) {
    size_t hbytes = (size_t)(N_NODES / nchunks) * HID * sizeof(unsigned short);
    if (off + hbytes <= ws_size) break;
    nchunks <<= 1;
  }
  int Mc = N_NODES / nchunks;
  unsigned short* h = (unsigned short*)alloc((size_t)Mc * HID * sizeof(unsigned short));

  hipMemsetAsync(cnt, 0, N_NODES * sizeof(int), stream);
  detect_kernel<<<1, 256, 0, stream>>>(eb, flagp);
  count_kernel<<<(N_EDGES + 255) / 256, 256, 0, stream>>>(eb, flagp, cnt);
  int nblk = (N_NODES + 255) / 256;
  scan1_kernel<<<nblk, 256, 0, stream>>>(cnt, ptr, bsum);
  scan2_kernel<<<1, 256, 0, stream>>>(bsum, nblk);
  scan3_kernel<<<nblk, 256, 0, stream>>>(ptr, bsum);
  dinv_kernel<<<nblk, 256, 0, stream>>>(cnt, ptr, dinv, selfw, cursor);
  fill_kernel<<<(N_EDGES + 255) / 256, 256, 0, stream>>>(eb, flagp, dinv, cursor, epack);
  prep_w<<<(F_INDIM * HID + HID * N_CLS + 255) / 256, 256, 0, stream>>>(W1, W2, W1T, W2T);

  for (int ci = 0; ci < nchunks; ++ci) {
    const float* Achunk = x + (size_t)ci * Mc * F_INDIM;
    dim3 g1((Mc + 63) / 64, HID / 128);
    gemm1_mfma<<<g1, 256, 0, stream>>>(Achunk, W1T, b1, h, Mc);
    dim3 g2((Mc + 63) / 64);
    gemm2_mfma<<<g2, 256, 0, stream>>>(h, W2T, b2,
        (unsigned short*)x0h, ci * Mc, Mc);
  }

  int pgrid = (N_NODES + NPB - 1) / NPB;  // 1786
  const unsigned int* zin = x0h;
  unsigned int* zo[2] = {z1, z2};
  for (int s = 0; s < K_STEPS - 1; ++s) {
    unsigned int* zout = zo[s & 1];
    prop_step<false><<<pgrid, 256, 0, stream>>>(zin, x0h, selfw, ptr, epack, zout, nullptr);
    zin = zout;
  }
  prop_step<true><<<pgrid, 256, 0, stream>>>(zin, x0h, selfw, ptr, epack, nullptr, out);
}